// Round 5
// baseline (398.577 us; speedup 1.0000x reference)
//
#include <hip/hip_runtime.h>
#include <hip/hip_bf16.h>
#include <stdint.h>

// Problem constants (fixed by setup_inputs)
#define B_SZ  8
#define N_Q   8192
#define M_PT  2048
#define C1    128
#define C2    256
#define CIN   384      // C1 + C2
#define H_OUT 256
#define R_TOT 65536    // B_SZ * N_Q

#define QPB   32             // queries per gather block

typedef __bf16 bf16x8 __attribute__((ext_vector_type(8)));
typedef __bf16 bf16x4 __attribute__((ext_vector_type(4)));
typedef __bf16 bf16x2 __attribute__((ext_vector_type(2)));
typedef float  f32x4  __attribute__((ext_vector_type(4)));

// Async global->LDS, 16B per lane. LDS dest is wave-uniform base + lane*16.
__device__ __forceinline__ void async_copy16(const void* g, void* l) {
    __builtin_amdgcn_global_load_lds(
        (const __attribute__((address_space(1))) unsigned int*)g,
        (__attribute__((address_space(3))) unsigned int*)l,
        16, 0, 0);
}

// ---------------------------------------------------------------------------
// KNN fused: one block = 256 queries vs full M (32 KB LDS), three phases:
//   0) weight fp32->bf16 conversion spread over the grid (65536 threads)
//   1) values-only top-3 scan (pure fma+min/med3: VALU-issue-bound ~12cyc/it,
//      fine at 1 block/CU — R3 measured VALUBusy 98% for this loop shape)
//   2) weights from (v_k + |q|^2)
//   3) index recovery rescan, bitwise-identical d' (same LDS data, same fmaf
//      chain), rare-hit exec-masked body (~3/2048 per lane)
// Replaces 3 kernels + 31 MB of vals4/ci4 global roundtrip.
// grid = 256 blocks of 256.
// ---------------------------------------------------------------------------
__global__ __launch_bounds__(256) void knn_fused(
    const float* __restrict__ xyz1, const float* __restrict__ xyz2,
    const float* __restrict__ W1,   const float* __restrict__ W2,
    __bf16* __restrict__ wb1,       __bf16* __restrict__ wb2,
    float4* __restrict__ w4,        int4* __restrict__ ci4) {
    __shared__ float4 pos[M_PT];        // 32 KB
    const int tid = threadIdx.x;
    const int b   = blockIdx.x >> 5;
    const int qb  = blockIdx.x & 31;

    // phase 0: weight conversion (no barrier needed; consumed by later dispatch)
    {
        const int g = blockIdx.x * 256 + tid;          // 0..65535
        wb1[g] = (__bf16)W1[g];
        if (g < H_OUT * CIN - R_TOT) wb1[R_TOT + g] = (__bf16)W1[R_TOT + g];
        wb2[g] = (__bf16)W2[g];
    }

    // stage (-2x,-2y,-2z,|p|^2) for the whole batch-b point set
    const float* x2 = xyz2 + (size_t)b * M_PT * 3;
    for (int j = tid; j < M_PT; j += 256) {
        float x = x2[j * 3], y = x2[j * 3 + 1], z = x2[j * 3 + 2];
        pos[j] = make_float4(-2.f * x, -2.f * y, -2.f * z,
                             fmaf(x, x, fmaf(y, y, z * z)));
    }
    __syncthreads();

    const int q = b * N_Q + qb * 256 + tid;
    const float* q1 = xyz1 + (size_t)q * 3;
    const float x1 = q1[0], y1 = q1[1], z1 = q1[2];

    // phase 1: values-only top-3
    float v0 = 3.4e38f, v1 = 3.4e38f, v2 = 3.4e38f;
#pragma unroll 8
    for (int j = 0; j < M_PT; ++j) {
        float4 p = pos[j];
        float d  = fmaf(p.x, x1, fmaf(p.y, y1, fmaf(p.z, z1, p.w)));
        float n0 = fminf(d, v0);
        float n1 = __builtin_amdgcn_fmed3f(d, v0, v1);
        float n2 = __builtin_amdgcn_fmed3f(d, v1, v2);
        v0 = n0; v1 = n1; v2 = n2;
    }

    // phase 2: inverse-distance weights (d_k = v_k + |q|^2)
    {
        float n1q = fmaf(x1, x1, fmaf(y1, y1, z1 * z1));
        float r0 = 1.f / ((v0 + n1q) + 1e-8f);
        float r1 = 1.f / ((v1 + n1q) + 1e-8f);
        float r2 = 1.f / ((v2 + n1q) + 1e-8f);
        float rs = 1.f / (r0 + r1 + r2);
        w4[q] = make_float4(r0 * rs, r1 * rs, r2 * rs, 0.f);
    }

    // phase 3: index recovery (bitwise-identical d'; min keeps earliest j,
    // matching jax top_k's lowest-index tie order)
    int i0 = 0x7fffffff, i1 = 0x7fffffff, i2 = 0x7fffffff;
#pragma unroll 4
    for (int j = 0; j < M_PT; ++j) {
        float4 p = pos[j];
        float d  = fmaf(p.x, x1, fmaf(p.y, y1, fmaf(p.z, z1, p.w)));
        if (d <= v2) {               // rare: exec-mask + execz skip
            i0 = min(i0, (d == v0) ? j : 0x7fffffff);
            i1 = min(i1, (d == v1) ? j : 0x7fffffff);
            i2 = min(i2, (d == v2) ? j : 0x7fffffff);
        }
    }
    ci4[q] = make_int4(i0, i1, i2, 0);
}

// ---------------------------------------------------------------------------
// Gather + concat -> xb (bf16 [R_TOT x CIN]).  grid = R_TOT/QPB = 2048.
// ---------------------------------------------------------------------------
__global__ __launch_bounds__(256) void interp_gather(
    const float* __restrict__ p1,  const float* __restrict__ p2,
    const int4* __restrict__ ci4,  const float4* __restrict__ w4,
    __bf16* __restrict__ xb) {
    __shared__ float wgt[QPB * 3];
    __shared__ int   ids[QPB * 3];

    const int tid = threadIdx.x;
    const int b   = blockIdx.x >> 8;            // 256 blocks per batch
    const int q0  = (blockIdx.x & 255) * QPB;

    if (tid < QPB) {
        const int q = b * N_Q + q0 + tid;
        int4   ii = ci4[q];
        float4 w  = w4[q];
        wgt[tid * 3] = w.x;  wgt[tid * 3 + 1] = w.y;  wgt[tid * 3 + 2] = w.z;
        ids[tid * 3] = ii.x; ids[tid * 3 + 1] = ii.y; ids[tid * 3 + 2] = ii.z;
    }
    __syncthreads();

    // wave-per-query cooperative gather (coalesced 1KB row reads)
    const int wave = tid >> 6, lane = tid & 63;
    const float* p2b = p2 + (size_t)b * M_PT * C2;
    const float* p1b = p1 + (size_t)(b * N_Q + q0) * C1;
    __bf16* outp = xb + (size_t)(b * N_Q + q0) * CIN;
    for (int qq = wave; qq < QPB; qq += 4) {
        float w0 = wgt[qq * 3], w1 = wgt[qq * 3 + 1], w2 = wgt[qq * 3 + 2];
        int   j0 = ids[qq * 3], j1 = ids[qq * 3 + 1], j2 = ids[qq * 3 + 2];
        const float4* ra = (const float4*)(p2b + (size_t)j0 * C2);
        const float4* rb = (const float4*)(p2b + (size_t)j1 * C2);
        const float4* rc = (const float4*)(p2b + (size_t)j2 * C2);
        float4 va = ra[lane], vb = rb[lane], vc = rc[lane];
        bf16x4 o;
        o[0] = (__bf16)(w0 * va.x + w1 * vb.x + w2 * vc.x);
        o[1] = (__bf16)(w0 * va.y + w1 * vb.y + w2 * vc.y);
        o[2] = (__bf16)(w0 * va.z + w1 * vb.z + w2 * vc.z);
        o[3] = (__bf16)(w0 * va.w + w1 * vb.w + w2 * vc.w);
        *(bf16x4*)(outp + (size_t)qq * CIN + C1 + lane * 4) = o;
        float2 pv = ((const float2*)(p1b + (size_t)qq * C1))[lane];
        bf16x2 o2; o2[0] = (__bf16)pv.x; o2[1] = (__bf16)pv.y;
        *(bf16x2*)(outp + (size_t)qq * CIN + lane * 2) = o2;
    }
}

// ---------------------------------------------------------------------------
// bf16 MFMA GEMM + fused BN-stats partials: C[r,o] = sum_k A[r,k]*Bw[o,k]
// m97 structure: 128x128 tile, 4 waves each 64x64, BK=32, global_load_lds x16B
// Output is bf16 (both layers): halves C-write traffic; BN applies later.
// grid: 1024 blocks of 256.
// ---------------------------------------------------------------------------
template <int K>
__global__ __launch_bounds__(256, 2) void gemm_bt(const __bf16* __restrict__ A,
                                                  const __bf16* __restrict__ Bw,
                                                  __bf16* __restrict__ Cout,
                                                  float* __restrict__ partS,
                                                  float* __restrict__ partQ) {
    __shared__ __attribute__((aligned(16))) __bf16 As[128 * 32];
    __shared__ __attribute__((aligned(16))) __bf16 Bs[128 * 32];
    const int tid  = threadIdx.x;
    const int wave = tid >> 6, lane = tid & 63;
    const int wm = wave >> 1, wn = wave & 1;
    const int quad = lane >> 4, r16 = lane & 15;
    const int bx = blockIdx.x & 1, by = blockIdx.x >> 1;
    const int l4 = lane >> 2, lk = (lane & 3) * 8;

    f32x4 acc[4][4] = {};

    const __bf16* gA = A  + (size_t)(by * 128 + wave * 32 + l4) * K + lk;
    const __bf16* gB = Bw + (size_t)(bx * 128 + wave * 32 + l4) * K + lk;
    char* lA = (char*)As + wave * 2048;
    char* lB = (char*)Bs + wave * 2048;

    for (int k0 = 0; k0 < K; k0 += 32) {
        async_copy16(gA + k0,                  lA);
        async_copy16(gA + k0 + (size_t)16 * K, lA + 1024);
        async_copy16(gB + k0,                  lB);
        async_copy16(gB + k0 + (size_t)16 * K, lB + 1024);
        __syncthreads();

        bf16x8 af[4], bf[4];
#pragma unroll
        for (int t = 0; t < 4; ++t)
            af[t] = *(const bf16x8*)(As + (wm * 64 + t * 16 + r16) * 32 + quad * 8);
#pragma unroll
        for (int u = 0; u < 4; ++u)
            bf[u] = *(const bf16x8*)(Bs + (wn * 64 + u * 16 + r16) * 32 + quad * 8);
#pragma unroll
        for (int t = 0; t < 4; ++t)
#pragma unroll
            for (int u = 0; u < 4; ++u)
                acc[t][u] = __builtin_amdgcn_mfma_f32_16x16x32_bf16(af[t], bf[u], acc[t][u], 0, 0, 0);
        __syncthreads();
    }

    // C/D layout col=lane&15, row=(lane>>4)*4+reg [m89-verified]
#pragma unroll
    for (int t = 0; t < 4; ++t) {
#pragma unroll
        for (int u = 0; u < 4; ++u) {
            const int col = bx * 128 + wn * 64 + u * 16 + r16;
#pragma unroll
            for (int r = 0; r < 4; ++r) {
                const int row = by * 128 + wm * 64 + t * 16 + quad * 4 + r;
                Cout[(size_t)row * H_OUT + col] = (__bf16)acc[t][u][r];
            }
        }
    }

    // fused BN-stats partials (reuse As as 8 KB reduction scratch)
    float* redS = (float*)As;          // [col(128)][slot(8)]
    float* redQ = ((float*)As) + 1024;
    const int slot = wm * 4 + quad;
#pragma unroll
    for (int u = 0; u < 4; ++u) {
        float s = 0.f, qq = 0.f;
#pragma unroll
        for (int t = 0; t < 4; ++t)
#pragma unroll
            for (int r = 0; r < 4; ++r) { float v = acc[t][u][r]; s += v; qq = fmaf(v, v, qq); }
        const int col = wn * 64 + u * 16 + r16;
        redS[col * 8 + slot] = s;
        redQ[col * 8 + slot] = qq;
    }
    __syncthreads();
    if (tid < 128) {
        float s = 0.f, qq = 0.f;
#pragma unroll
        for (int k = 0; k < 8; ++k) { s += redS[tid * 8 + k]; qq += redQ[tid * 8 + k]; }
        partS[(size_t)blockIdx.x * 128 + tid] = s;
        partQ[(size_t)blockIdx.x * 128 + tid] = qq;
    }
}

// ---------------------------------------------------------------------------
// fold per-block partials -> per-channel scale/shift.  One block per channel.
// channel c lives in gemm-blocks bid = p*2 + (c>>7), entry (c&127); p<512.
// NB: stats are computed on pre-bf16-rounding fp32 accumulators; applied to
// bf16-rounded y — error ~2^-9 relative, well inside threshold.
// ---------------------------------------------------------------------------
__global__ __launch_bounds__(256) void bn_finalize(const float* __restrict__ pS,
                                                   const float* __restrict__ pQ,
                                                   const float* __restrict__ gamma,
                                                   const float* __restrict__ beta,
                                                   float* __restrict__ sc,
                                                   float* __restrict__ sh) {
    __shared__ float rs[256], rq[256];
    const int c = blockIdx.x;
    const int t = threadIdx.x;
    const int half = c >> 7, lo = c & 127;
    const size_t o1 = (size_t)(2 * t + half) * 128 + lo;
    const size_t o2 = (size_t)(2 * (t + 256) + half) * 128 + lo;
    rs[t] = pS[o1] + pS[o2];
    rq[t] = pQ[o1] + pQ[o2];
    __syncthreads();
    for (int k = 128; k > 0; k >>= 1) {
        if (t < k) { rs[t] += rs[t + k]; rq[t] += rq[t + k]; }
        __syncthreads();
    }
    if (t == 0) {
        const float inv = 1.f / (float)R_TOT;
        float mean = rs[0] * inv;
        float var  = rq[0] * inv - mean * mean;
        float a    = gamma[c] * rsqrtf(var + 1e-5f);
        sc[c] = a;
        sh[c] = beta[c] - mean * a;
    }
}

// ---------------------------------------------------------------------------
// apply BN+ReLU in place (bf16, layer-1 intermediate)
// ---------------------------------------------------------------------------
__global__ __launch_bounds__(256) void apply_bf16(__bf16* __restrict__ y,
                                                  const float* __restrict__ sc,
                                                  const float* __restrict__ sh) {
    __shared__ float scs[256], shs[256];
    scs[threadIdx.x] = sc[threadIdx.x];
    shs[threadIdx.x] = sh[threadIdx.x];
    __syncthreads();
    size_t i = ((size_t)blockIdx.x * 256 + threadIdx.x) * 8;
    int c0 = (int)(i & 255);
    bf16x8 v = *(const bf16x8*)(y + i);
#pragma unroll
    for (int e = 0; e < 8; ++e) {
        float f = fmaf((float)v[e], scs[c0 + e], shs[c0 + e]);
        v[e] = (__bf16)fmaxf(f, 0.f);
    }
    *(bf16x8*)(y + i) = v;
}

// ---------------------------------------------------------------------------
// apply BN+ReLU reading bf16 y2, writing fp32 output (saves the 64 MB fp32
// pre-BN roundtrip: 192 MB -> 130 MB for the layer-2 epilogue)
// ---------------------------------------------------------------------------
__global__ __launch_bounds__(256) void apply_out(const __bf16* __restrict__ y,
                                                 const float* __restrict__ sc,
                                                 const float* __restrict__ sh,
                                                 float* __restrict__ out) {
    __shared__ float scs[256], shs[256];
    scs[threadIdx.x] = sc[threadIdx.x];
    shs[threadIdx.x] = sh[threadIdx.x];
    __syncthreads();
    size_t i = ((size_t)blockIdx.x * 256 + threadIdx.x) * 8;
    int c0 = (int)(i & 255);
    bf16x8 v = *(const bf16x8*)(y + i);
    f32x4 o0, o1;
#pragma unroll
    for (int e = 0; e < 4; ++e)
        o0[e] = fmaxf(fmaf((float)v[e], scs[c0 + e], shs[c0 + e]), 0.f);
#pragma unroll
    for (int e = 0; e < 4; ++e)
        o1[e] = fmaxf(fmaf((float)v[4 + e], scs[c0 + 4 + e], shs[c0 + 4 + e]), 0.f);
    *(f32x4*)(out + i)     = o0;
    *(f32x4*)(out + i + 4) = o1;
}

// ---------------------------------------------------------------------------
extern "C" void kernel_launch(void* const* d_in, const int* in_sizes, int n_in,
                              void* d_out, int out_size, void* d_ws, size_t ws_size,
                              hipStream_t stream) {
    const float* xyz1 = (const float*)d_in[0];
    const float* xyz2 = (const float*)d_in[1];
    const float* p1   = (const float*)d_in[2];
    const float* p2   = (const float*)d_in[3];
    const float* W1   = (const float*)d_in[4];
    // d_in[5] = b1  (cancels in batch-norm)
    const float* g1   = (const float*)d_in[6];
    const float* be1  = (const float*)d_in[7];
    const float* W2   = (const float*)d_in[8];
    // d_in[9] = b2  (cancels in batch-norm)
    const float* g2   = (const float*)d_in[10];
    const float* be2  = (const float*)d_in[11];
    float* out = (float*)d_out;

    // workspace layout (16B aligned), max offset ~84.3 MB (same as R4):
    //   xb   @ 0        (50 MB)  — dead after GEMM1; y2b + partS2 overlay it
    //   y1b  @ 50331648 (33 MB)  — w4/ci4 overlay its head until GEMM1 runs
    char* ws = (char*)d_ws;
    __bf16* xb     = (__bf16*)(ws);
    __bf16* y1b    = (__bf16*)(ws + 50331648);
    float4* w4     = (float4*)(ws + 50331648);         // 1 MB (dead pre-GEMM1)
    int4*   ci4    = (int4*)  (ws + 51380224);         // 1 MB (dead pre-GEMM1)
    __bf16* y2b    = (__bf16*)(ws);                    // 33 MB over dead xb
    float*  partS2 = (float*) (ws + 35651584);         // xb tail, dead region
    float*  partQ2 = partS2 + 131072;
    __bf16* wb1    = (__bf16*)(ws + 83886080);         // 256*384*2
    __bf16* wb2    = (__bf16*)(ws + 84082688);         // 256*256*2
    float*  sc1    = (float*) (ws + 84213760);
    float*  sh1    = sc1 + 256;
    float*  sc2    = sc1 + 512;
    float*  sh2    = sc1 + 768;

    float* partS1 = (float*)d_out;            // d_out (64 MB) dead until apply_out
    float* partQ1 = partS1 + 131072;

    knn_fused<<<256, 256, 0, stream>>>(xyz1, xyz2, W1, W2, wb1, wb2, w4, ci4);
    interp_gather<<<R_TOT / QPB, 256, 0, stream>>>(p1, p2, ci4, w4, xb);

    gemm_bt<CIN><<<1024, 256, 0, stream>>>(xb, wb1, y1b, partS1, partQ1);
    bn_finalize<<<256, 256, 0, stream>>>(partS1, partQ1, g1, be1, sc1, sh1);
    apply_bf16<<<8192, 256, 0, stream>>>(y1b, sc1, sh1);

    gemm_bt<H_OUT><<<1024, 256, 0, stream>>>(y1b, wb2, y2b, partS2, partQ2);
    bn_finalize<<<256, 256, 0, stream>>>(partS2, partQ2, g2, be2, sc2, sh2);
    apply_out<<<8192, 256, 0, stream>>>(y2b, sc2, sh2, out);
}

// Round 6
// 274.920 us; speedup vs baseline: 1.4498x; 1.4498x over previous
//
#include <hip/hip_runtime.h>
#include <hip/hip_bf16.h>
#include <stdint.h>

// Problem constants (fixed by setup_inputs)
#define B_SZ  8
#define N_Q   8192
#define M_PT  2048
#define C1    128
#define C2    256
#define CIN   384      // C1 + C2
#define H_OUT 256
#define R_TOT 65536    // B_SZ * N_Q

#define NCH   8              // KNN chunks over M
#define CHM   (M_PT / NCH)   // 256 points per chunk
#define QPB   32             // queries per gather block

typedef __bf16 bf16x8 __attribute__((ext_vector_type(8)));
typedef __bf16 bf16x4 __attribute__((ext_vector_type(4)));
typedef __bf16 bf16x2 __attribute__((ext_vector_type(2)));
typedef float  f32x4  __attribute__((ext_vector_type(4)));

// Async global->LDS, 16B per lane. LDS dest is wave-uniform base + lane*16.
__device__ __forceinline__ void async_copy16(const void* g, void* l) {
    __builtin_amdgcn_global_load_lds(
        (const __attribute__((address_space(1))) unsigned int*)g,
        (__attribute__((address_space(3))) unsigned int*)l,
        16, 0, 0);
}

// ---------------------------------------------------------------------------
// KNN K1: values-only per-chunk top-3 (R4-proven shape: 2048 blocks, 4 KB
// LDS, 8 blocks/CU).  d' = |q-p|^2 - |q|^2.  Pure fma+min/med3 — no index
// tracking (R3: index cndmasks 2x-bloat codegen).
// ---------------------------------------------------------------------------
__global__ __launch_bounds__(256) void knn_vals(
    const float* __restrict__ xyz1, const float* __restrict__ xyz2,
    float4* __restrict__ vals4) {
    __shared__ float4 pos[CHM];
    const int tid = threadIdx.x;
    const int c   = blockIdx.x & (NCH - 1);
    const int qb  = (blockIdx.x >> 3) & 31;
    const int b   = blockIdx.x >> 8;
    {   // stage (-2x,-2y,-2z,|p|^2) — MUST match knn_recover bitwise
        const float* x2 = xyz2 + ((size_t)b * M_PT + c * CHM) * 3;
        float x = x2[tid * 3], y = x2[tid * 3 + 1], z = x2[tid * 3 + 2];
        pos[tid] = make_float4(-2.f * x, -2.f * y, -2.f * z,
                               fmaf(x, x, fmaf(y, y, z * z)));
    }
    __syncthreads();

    const int q = b * N_Q + qb * 256 + tid;
    const float* q1 = xyz1 + (size_t)q * 3;
    float x1 = q1[0], y1 = q1[1], z1 = q1[2];
    float v0 = 3.4e38f, v1 = 3.4e38f, v2 = 3.4e38f;
#pragma unroll 8
    for (int j = 0; j < CHM; ++j) {
        float4 p = pos[j];
        float d  = fmaf(p.x, x1, fmaf(p.y, y1, fmaf(p.z, z1, p.w)));
        float n0 = fminf(d, v0);
        float n1 = __builtin_amdgcn_fmed3f(d, v0, v1);
        float n2 = __builtin_amdgcn_fmed3f(d, v1, v2);
        v0 = n0; v1 = n1; v2 = n2;
    }
    vals4[(size_t)c * R_TOT + q] = make_float4(v0, v1, v2, 0.f);
}

// ---------------------------------------------------------------------------
// KNN K2: merge 8 chunk-triples -> global (v0,v1,v2) + interp weights.
// Also folds the fp32->bf16 weight conversion (65536 threads, 1:1).
// grid = 256 blocks of 256.
// ---------------------------------------------------------------------------
__global__ __launch_bounds__(256) void knn_merge(
    const float4* __restrict__ vals4, const float* __restrict__ xyz1,
    const float* __restrict__ W1,     const float* __restrict__ W2,
    __bf16* __restrict__ wb1,         __bf16* __restrict__ wb2,
    float4* __restrict__ v4,          float4* __restrict__ w4) {
    const int q = blockIdx.x * 256 + threadIdx.x;

    // weight conversion fold (consumed two dispatches later — no barrier needed)
    wb1[q] = (__bf16)W1[q];
    if (q < H_OUT * CIN - R_TOT) wb1[R_TOT + q] = (__bf16)W1[R_TOT + q];
    wb2[q] = (__bf16)W2[q];

    float v0 = 3.4e38f, v1 = 3.4e38f, v2 = 3.4e38f;
#pragma unroll
    for (int c = 0; c < NCH; ++c) {
        float4 t = vals4[(size_t)c * R_TOT + q];
#pragma unroll
        for (int k = 0; k < 3; ++k) {
            float d  = (k == 0) ? t.x : (k == 1) ? t.y : t.z;
            float n0 = fminf(d, v0);
            float n1 = __builtin_amdgcn_fmed3f(d, v0, v1);
            float n2 = __builtin_amdgcn_fmed3f(d, v1, v2);
            v0 = n0; v1 = n1; v2 = n2;
        }
    }
    const float* q1 = xyz1 + (size_t)q * 3;
    float x1 = q1[0], y1 = q1[1], z1 = q1[2];
    float n1q = fmaf(x1, x1, fmaf(y1, y1, z1 * z1));
    float r0 = 1.f / ((v0 + n1q) + 1e-8f);
    float r1 = 1.f / ((v1 + n1q) + 1e-8f);
    float r2 = 1.f / ((v2 + n1q) + 1e-8f);
    float rs = 1.f / (r0 + r1 + r2);
    v4[q] = make_float4(v0, v1, v2, 0.f);
    w4[q] = make_float4(r0 * rs, r1 * rs, r2 * rs, 0.f);
}

// ---------------------------------------------------------------------------
// KNN K3: index recovery.  Bitwise-identical d' rescan; equality-match vs
// global top-3.  Hit ~3/2048/lane -> exec-masked body rarely runs.
// grid = 2048 blocks of 256.
// ---------------------------------------------------------------------------
__global__ __launch_bounds__(256) void knn_recover(
    const float* __restrict__ xyz1, const float* __restrict__ xyz2,
    const float4* __restrict__ v4, int4* __restrict__ ci4) {
    __shared__ float4 pos[CHM];
    const int tid = threadIdx.x;
    const int c   = blockIdx.x & (NCH - 1);
    const int qb  = (blockIdx.x >> 3) & 31;
    const int b   = blockIdx.x >> 8;
    {   // identical staging to knn_vals
        const float* x2 = xyz2 + ((size_t)b * M_PT + c * CHM) * 3;
        float x = x2[tid * 3], y = x2[tid * 3 + 1], z = x2[tid * 3 + 2];
        pos[tid] = make_float4(-2.f * x, -2.f * y, -2.f * z,
                               fmaf(x, x, fmaf(y, y, z * z)));
    }
    __syncthreads();

    const int q = b * N_Q + qb * 256 + tid;
    const float* q1 = xyz1 + (size_t)q * 3;
    float x1 = q1[0], y1 = q1[1], z1 = q1[2];
    const float4 vv = v4[q];
    int i0 = 0x7fffffff, i1 = 0x7fffffff, i2 = 0x7fffffff;
    const int jb = c * CHM;
#pragma unroll 4
    for (int j = 0; j < CHM; ++j) {
        float4 p = pos[j];
        float d  = fmaf(p.x, x1, fmaf(p.y, y1, fmaf(p.z, z1, p.w)));
        if (d <= vv.z) {             // rare: exec-mask + execz skip
            const int jj = jb + j;   // j ascending -> min keeps earliest
            i0 = min(i0, (d == vv.x) ? jj : 0x7fffffff);
            i1 = min(i1, (d == vv.y) ? jj : 0x7fffffff);
            i2 = min(i2, (d == vv.z) ? jj : 0x7fffffff);
        }
    }
    ci4[(size_t)c * R_TOT + q] = make_int4(i0, i1, i2, 0);
}

// ---------------------------------------------------------------------------
// K4: fold chunk indices (global min per slot), then cooperative gather +
// concat -> xb (bf16 [R_TOT x CIN]).  grid = R_TOT/QPB = 2048.
// ---------------------------------------------------------------------------
__global__ __launch_bounds__(256) void interp_gather(
    const float* __restrict__ p1,  const float* __restrict__ p2,
    const int4* __restrict__ ci4,  const float4* __restrict__ w4,
    __bf16* __restrict__ xb) {
    __shared__ float wgt[QPB * 3];
    __shared__ int   ids[QPB * 3];

    const int tid = threadIdx.x;
    const int b   = blockIdx.x >> 8;            // 256 blocks per batch
    const int q0  = (blockIdx.x & 255) * QPB;

    if (tid < QPB) {
        const int q = b * N_Q + q0 + tid;
        int i0 = 0x7fffffff, i1 = 0x7fffffff, i2 = 0x7fffffff;
#pragma unroll
        for (int c = 0; c < NCH; ++c) {
            int4 t = ci4[(size_t)c * R_TOT + q];
            i0 = min(i0, t.x); i1 = min(i1, t.y); i2 = min(i2, t.z);
        }
        float4 w = w4[q];
        wgt[tid * 3] = w.x; wgt[tid * 3 + 1] = w.y; wgt[tid * 3 + 2] = w.z;
        ids[tid * 3] = i0;  ids[tid * 3 + 1] = i1;  ids[tid * 3 + 2] = i2;
    }
    __syncthreads();

    // wave-per-query cooperative gather (coalesced 1KB row reads)
    const int wave = tid >> 6, lane = tid & 63;
    const float* p2b = p2 + (size_t)b * M_PT * C2;
    const float* p1b = p1 + (size_t)(b * N_Q + q0) * C1;
    __bf16* outp = xb + (size_t)(b * N_Q + q0) * CIN;
    for (int qq = wave; qq < QPB; qq += 4) {
        float w0 = wgt[qq * 3], w1 = wgt[qq * 3 + 1], w2 = wgt[qq * 3 + 2];
        int   j0 = ids[qq * 3], j1 = ids[qq * 3 + 1], j2 = ids[qq * 3 + 2];
        const float4* ra = (const float4*)(p2b + (size_t)j0 * C2);
        const float4* rb = (const float4*)(p2b + (size_t)j1 * C2);
        const float4* rc = (const float4*)(p2b + (size_t)j2 * C2);
        float4 va = ra[lane], vb = rb[lane], vc = rc[lane];
        bf16x4 o;
        o[0] = (__bf16)(w0 * va.x + w1 * vb.x + w2 * vc.x);
        o[1] = (__bf16)(w0 * va.y + w1 * vb.y + w2 * vc.y);
        o[2] = (__bf16)(w0 * va.z + w1 * vb.z + w2 * vc.z);
        o[3] = (__bf16)(w0 * va.w + w1 * vb.w + w2 * vc.w);
        *(bf16x4*)(outp + (size_t)qq * CIN + C1 + lane * 4) = o;
        float2 pv = ((const float2*)(p1b + (size_t)qq * C1))[lane];
        bf16x2 o2; o2[0] = (__bf16)pv.x; o2[1] = (__bf16)pv.y;
        *(bf16x2*)(outp + (size_t)qq * CIN + lane * 2) = o2;
    }
}

// ---------------------------------------------------------------------------
// bf16 MFMA GEMM + fused BN-stats partials: C[r,o] = sum_k A[r,k]*Bw[o,k]
// m97 structure: 128x128 tile, 4 waves each 64x64, BK=32, global_load_lds x16B
// Output bf16 (both layers).  grid: 1024 blocks of 256.
// ---------------------------------------------------------------------------
template <int K>
__global__ __launch_bounds__(256, 2) void gemm_bt(const __bf16* __restrict__ A,
                                                  const __bf16* __restrict__ Bw,
                                                  __bf16* __restrict__ Cout,
                                                  float* __restrict__ partS,
                                                  float* __restrict__ partQ) {
    __shared__ __attribute__((aligned(16))) __bf16 As[128 * 32];
    __shared__ __attribute__((aligned(16))) __bf16 Bs[128 * 32];
    const int tid  = threadIdx.x;
    const int wave = tid >> 6, lane = tid & 63;
    const int wm = wave >> 1, wn = wave & 1;
    const int quad = lane >> 4, r16 = lane & 15;
    const int bx = blockIdx.x & 1, by = blockIdx.x >> 1;
    const int l4 = lane >> 2, lk = (lane & 3) * 8;

    f32x4 acc[4][4] = {};

    const __bf16* gA = A  + (size_t)(by * 128 + wave * 32 + l4) * K + lk;
    const __bf16* gB = Bw + (size_t)(bx * 128 + wave * 32 + l4) * K + lk;
    char* lA = (char*)As + wave * 2048;
    char* lB = (char*)Bs + wave * 2048;

    for (int k0 = 0; k0 < K; k0 += 32) {
        async_copy16(gA + k0,                  lA);
        async_copy16(gA + k0 + (size_t)16 * K, lA + 1024);
        async_copy16(gB + k0,                  lB);
        async_copy16(gB + k0 + (size_t)16 * K, lB + 1024);
        __syncthreads();

        bf16x8 af[4], bf[4];
#pragma unroll
        for (int t = 0; t < 4; ++t)
            af[t] = *(const bf16x8*)(As + (wm * 64 + t * 16 + r16) * 32 + quad * 8);
#pragma unroll
        for (int u = 0; u < 4; ++u)
            bf[u] = *(const bf16x8*)(Bs + (wn * 64 + u * 16 + r16) * 32 + quad * 8);
#pragma unroll
        for (int t = 0; t < 4; ++t)
#pragma unroll
            for (int u = 0; u < 4; ++u)
                acc[t][u] = __builtin_amdgcn_mfma_f32_16x16x32_bf16(af[t], bf[u], acc[t][u], 0, 0, 0);
        __syncthreads();
    }

    // C/D layout col=lane&15, row=(lane>>4)*4+reg [m89-verified]
#pragma unroll
    for (int t = 0; t < 4; ++t) {
#pragma unroll
        for (int u = 0; u < 4; ++u) {
            const int col = bx * 128 + wn * 64 + u * 16 + r16;
#pragma unroll
            for (int r = 0; r < 4; ++r) {
                const int row = by * 128 + wm * 64 + t * 16 + quad * 4 + r;
                Cout[(size_t)row * H_OUT + col] = (__bf16)acc[t][u][r];
            }
        }
    }

    // fused BN-stats partials (reuse As as 8 KB reduction scratch)
    float* redS = (float*)As;          // [col(128)][slot(8)]
    float* redQ = ((float*)As) + 1024;
    const int slot = wm * 4 + quad;
#pragma unroll
    for (int u = 0; u < 4; ++u) {
        float s = 0.f, qq = 0.f;
#pragma unroll
        for (int t = 0; t < 4; ++t)
#pragma unroll
            for (int r = 0; r < 4; ++r) { float v = acc[t][u][r]; s += v; qq = fmaf(v, v, qq); }
        const int col = wn * 64 + u * 16 + r16;
        redS[col * 8 + slot] = s;
        redQ[col * 8 + slot] = qq;
    }
    __syncthreads();
    if (tid < 128) {
        float s = 0.f, qq = 0.f;
#pragma unroll
        for (int k = 0; k < 8; ++k) { s += redS[tid * 8 + k]; qq += redQ[tid * 8 + k]; }
        partS[(size_t)blockIdx.x * 128 + tid] = s;
        partQ[(size_t)blockIdx.x * 128 + tid] = qq;
    }
}

// ---------------------------------------------------------------------------
// fold per-block partials -> per-channel scale/shift.  One block per channel.
// channel c lives in gemm-blocks bid = p*2 + (c>>7), entry (c&127); p<512.
// ---------------------------------------------------------------------------
__global__ __launch_bounds__(256) void bn_finalize(const float* __restrict__ pS,
                                                   const float* __restrict__ pQ,
                                                   const float* __restrict__ gamma,
                                                   const float* __restrict__ beta,
                                                   float* __restrict__ sc,
                                                   float* __restrict__ sh) {
    __shared__ float rs[256], rq[256];
    const int c = blockIdx.x;
    const int t = threadIdx.x;
    const int half = c >> 7, lo = c & 127;
    const size_t o1 = (size_t)(2 * t + half) * 128 + lo;
    const size_t o2 = (size_t)(2 * (t + 256) + half) * 128 + lo;
    rs[t] = pS[o1] + pS[o2];
    rq[t] = pQ[o1] + pQ[o2];
    __syncthreads();
    for (int k = 128; k > 0; k >>= 1) {
        if (t < k) { rs[t] += rs[t + k]; rq[t] += rq[t + k]; }
        __syncthreads();
    }
    if (t == 0) {
        const float inv = 1.f / (float)R_TOT;
        float mean = rs[0] * inv;
        float var  = rq[0] * inv - mean * mean;
        float a    = gamma[c] * rsqrtf(var + 1e-5f);
        sc[c] = a;
        sh[c] = beta[c] - mean * a;
    }
}

// ---------------------------------------------------------------------------
// apply BN+ReLU in place (bf16, layer-1 intermediate)
// ---------------------------------------------------------------------------
__global__ __launch_bounds__(256) void apply_bf16(__bf16* __restrict__ y,
                                                  const float* __restrict__ sc,
                                                  const float* __restrict__ sh) {
    __shared__ float scs[256], shs[256];
    scs[threadIdx.x] = sc[threadIdx.x];
    shs[threadIdx.x] = sh[threadIdx.x];
    __syncthreads();
    size_t i = ((size_t)blockIdx.x * 256 + threadIdx.x) * 8;
    int c0 = (int)(i & 255);
    bf16x8 v = *(const bf16x8*)(y + i);
#pragma unroll
    for (int e = 0; e < 8; ++e) {
        float f = fmaf((float)v[e], scs[c0 + e], shs[c0 + e]);
        v[e] = (__bf16)fmaxf(f, 0.f);
    }
    *(bf16x8*)(y + i) = v;
}

// ---------------------------------------------------------------------------
// apply BN+ReLU reading bf16 y2, writing fp32 output
// ---------------------------------------------------------------------------
__global__ __launch_bounds__(256) void apply_out(const __bf16* __restrict__ y,
                                                 const float* __restrict__ sc,
                                                 const float* __restrict__ sh,
                                                 float* __restrict__ out) {
    __shared__ float scs[256], shs[256];
    scs[threadIdx.x] = sc[threadIdx.x];
    shs[threadIdx.x] = sh[threadIdx.x];
    __syncthreads();
    size_t i = ((size_t)blockIdx.x * 256 + threadIdx.x) * 8;
    int c0 = (int)(i & 255);
    bf16x8 v = *(const bf16x8*)(y + i);
    f32x4 o0, o1;
#pragma unroll
    for (int e = 0; e < 4; ++e)
        o0[e] = fmaxf(fmaf((float)v[e], scs[c0 + e], shs[c0 + e]), 0.f);
#pragma unroll
    for (int e = 0; e < 4; ++e)
        o1[e] = fmaxf(fmaf((float)v[4 + e], scs[c0 + 4 + e], shs[c0 + 4 + e]), 0.f);
    *(f32x4*)(out + i)     = o0;
    *(f32x4*)(out + i + 4) = o1;
}

// ---------------------------------------------------------------------------
extern "C" void kernel_launch(void* const* d_in, const int* in_sizes, int n_in,
                              void* d_out, int out_size, void* d_ws, size_t ws_size,
                              hipStream_t stream) {
    const float* xyz1 = (const float*)d_in[0];
    const float* xyz2 = (const float*)d_in[1];
    const float* p1   = (const float*)d_in[2];
    const float* p2   = (const float*)d_in[3];
    const float* W1   = (const float*)d_in[4];
    // d_in[5] = b1  (cancels in batch-norm)
    const float* g1   = (const float*)d_in[6];
    const float* be1  = (const float*)d_in[7];
    const float* W2   = (const float*)d_in[8];
    // d_in[9] = b2  (cancels in batch-norm)
    const float* g2   = (const float*)d_in[10];
    const float* be2  = (const float*)d_in[11];
    float* out = (float*)d_out;

    // workspace layout (16B aligned), max offset ~84.3 MB:
    //   xb @0 (50 MB) — dead after GEMM1; y2b + partS2 overlay it
    //   y1b @50331648 (33.5 MB) — KNN scratch overlays it until GEMM1 writes
    char* ws = (char*)d_ws;
    __bf16* xb     = (__bf16*)(ws);
    __bf16* y1b    = (__bf16*)(ws + 50331648);
    float4* vals4  = (float4*)(ws + 50331648);         // 8 MB  (pre-GEMM1)
    int4*   ci4    = (int4*)  (ws + 58720256);         // 8 MB  (pre-GEMM1)
    float4* v4     = (float4*)(ws + 67108864);         // 1 MB
    float4* w4     = (float4*)(ws + 68157440);         // 1 MB
    __bf16* y2b    = (__bf16*)(ws);                    // 33.5 MB over dead xb
    float*  partS2 = (float*) (ws + 35651584);         // xb tail (dead)
    float*  partQ2 = partS2 + 131072;
    __bf16* wb1    = (__bf16*)(ws + 83886080);         // 256*384*2
    __bf16* wb2    = (__bf16*)(ws + 84082688);         // 256*256*2
    float*  sc1    = (float*) (ws + 84213760);
    float*  sh1    = sc1 + 256;
    float*  sc2    = sc1 + 512;
    float*  sh2    = sc1 + 768;

    float* partS1 = (float*)d_out;            // d_out dead until apply_out
    float* partQ1 = partS1 + 131072;

    knn_vals<<<B_SZ * 32 * NCH, 256, 0, stream>>>(xyz1, xyz2, vals4);
    knn_merge<<<R_TOT / 256, 256, 0, stream>>>(vals4, xyz1, W1, W2, wb1, wb2, v4, w4);
    knn_recover<<<B_SZ * 32 * NCH, 256, 0, stream>>>(xyz1, xyz2, v4, ci4);
    interp_gather<<<R_TOT / QPB, 256, 0, stream>>>(p1, p2, ci4, w4, xb);

    gemm_bt<CIN><<<1024, 256, 0, stream>>>(xb, wb1, y1b, partS1, partQ1);
    bn_finalize<<<256, 256, 0, stream>>>(partS1, partQ1, g1, be1, sc1, sh1);
    apply_bf16<<<8192, 256, 0, stream>>>(y1b, sc1, sh1);

    gemm_bt<H_OUT><<<1024, 256, 0, stream>>>(y1b, wb2, y2b, partS2, partQ2);
    bn_finalize<<<256, 256, 0, stream>>>(partS2, partQ2, g2, be2, sc2, sh2);
    apply_out<<<8192, 256, 0, stream>>>(y2b, sc2, sh2, out);
}

// Round 7
// 261.706 us; speedup vs baseline: 1.5230x; 1.0505x over previous
//
#include <hip/hip_runtime.h>
#include <hip/hip_bf16.h>
#include <stdint.h>

// Problem constants (fixed by setup_inputs)
#define B_SZ  8
#define N_Q   8192
#define M_PT  2048
#define C1    128
#define C2    256
#define CIN   384      // C1 + C2
#define H_OUT 256
#define R_TOT 65536    // B_SZ * N_Q

#define NCH   8              // KNN chunks over M
#define CHM   (M_PT / NCH)   // 256 points per chunk

typedef __bf16 bf16x8 __attribute__((ext_vector_type(8)));
typedef __bf16 bf16x4 __attribute__((ext_vector_type(4)));
typedef float  f32x4  __attribute__((ext_vector_type(4)));

// Async global->LDS, 16B per lane. LDS dest is wave-uniform base + lane*16.
__device__ __forceinline__ void async_copy16(const void* g, void* l) {
    __builtin_amdgcn_global_load_lds(
        (const __attribute__((address_space(1))) unsigned int*)g,
        (__attribute__((address_space(3))) unsigned int*)l,
        16, 0, 0);
}

// ---------------------------------------------------------------------------
// KNN K1: values-only per-chunk top-3 (R4/R6-proven shape: 2048 blocks, 4 KB
// LDS, 8 blocks/CU, VALUBusy~98%).  Folds: p2->bf16 (all blocks, 8/thread),
// W1 split-convert to wb1a|wb1b (blocks<384), W2 convert (blocks 384..639).
// ---------------------------------------------------------------------------
__global__ __launch_bounds__(256) void knn_vals(
    const float* __restrict__ xyz1, const float* __restrict__ xyz2,
    const float* __restrict__ p2,   const float* __restrict__ W1,
    const float* __restrict__ W2,
    __bf16* __restrict__ p2b,  __bf16* __restrict__ wb1a,
    __bf16* __restrict__ wb1b, __bf16* __restrict__ wb2,
    float4* __restrict__ vals4) {
    __shared__ float4 pos[CHM];
    const int tid = threadIdx.x;
    const int c   = blockIdx.x & (NCH - 1);
    const int qb  = (blockIdx.x >> 3) & 31;
    const int b   = blockIdx.x >> 8;
    const int gid = blockIdx.x * 256 + tid;

    // fold: p2 -> bf16 (4,194,304 elems = 524288 threads x 8)
    {
        const float4* src = (const float4*)p2 + (size_t)gid * 2;
        float4 a = src[0], bb = src[1];
        bf16x8 o;
        o[0]=(__bf16)a.x; o[1]=(__bf16)a.y; o[2]=(__bf16)a.z; o[3]=(__bf16)a.w;
        o[4]=(__bf16)bb.x; o[5]=(__bf16)bb.y; o[6]=(__bf16)bb.z; o[7]=(__bf16)bb.w;
        *(bf16x8*)(p2b + (size_t)gid * 8) = o;
    }
    // fold: W1 split-convert (98304 elems) / W2 convert (65536 elems)
    if (blockIdx.x < 384) {
        const int e = gid;                       // 0..98303
        const int o = e / 384, k = e - o * 384;
        __bf16 v = (__bf16)W1[e];
        if (k < C1) wb1a[o * C1 + k] = v;
        else        wb1b[o * C2 + (k - C1)] = v;
    } else if (blockIdx.x < 640) {
        const int e = gid - 98304;               // 0..65535
        wb2[e] = (__bf16)W2[e];
    }

    {   // stage (-2x,-2y,-2z,|p|^2) — MUST match knn_recover bitwise
        const float* x2 = xyz2 + ((size_t)b * M_PT + c * CHM) * 3;
        float x = x2[tid * 3], y = x2[tid * 3 + 1], z = x2[tid * 3 + 2];
        pos[tid] = make_float4(-2.f * x, -2.f * y, -2.f * z,
                               fmaf(x, x, fmaf(y, y, z * z)));
    }
    __syncthreads();

    const int q = b * N_Q + qb * 256 + tid;
    const float* q1 = xyz1 + (size_t)q * 3;
    float x1 = q1[0], y1 = q1[1], z1 = q1[2];
    float v0 = 3.4e38f, v1 = 3.4e38f, v2 = 3.4e38f;
#pragma unroll 8
    for (int j = 0; j < CHM; ++j) {
        float4 p = pos[j];
        float d  = fmaf(p.x, x1, fmaf(p.y, y1, fmaf(p.z, z1, p.w)));
        float n0 = fminf(d, v0);
        float n1 = __builtin_amdgcn_fmed3f(d, v0, v1);
        float n2 = __builtin_amdgcn_fmed3f(d, v1, v2);
        v0 = n0; v1 = n1; v2 = n2;
    }
    vals4[(size_t)c * R_TOT + q] = make_float4(v0, v1, v2, 0.f);
}

// ---------------------------------------------------------------------------
// KNN K2: merge (folded in, was knn_merge: chunk-ascending min/med3 over the
// 24 candidates — bitwise-selects, so equality-recovery stays exact) +
// weights (c==0 writes) + index-recovery rescan -> ci4[c][q].
// Folds: p1->bf16 (8,388,608 elems = 524288 threads x 16).
// ---------------------------------------------------------------------------
__global__ __launch_bounds__(256) void knn_recover(
    const float* __restrict__ xyz1, const float* __restrict__ xyz2,
    const float* __restrict__ p1,   const float4* __restrict__ vals4,
    __bf16* __restrict__ p1b, float4* __restrict__ w4,
    int4* __restrict__ ci4) {
    __shared__ float4 pos[CHM];
    const int tid = threadIdx.x;
    const int c   = blockIdx.x & (NCH - 1);
    const int qb  = (blockIdx.x >> 3) & 31;
    const int b   = blockIdx.x >> 8;
    const int gid = blockIdx.x * 256 + tid;

    // fold: p1 -> bf16
    {
        const float4* src = (const float4*)p1 + (size_t)gid * 4;
        float4 a = src[0], bb = src[1], cc = src[2], dd = src[3];
        bf16x8 o0, o1;
        o0[0]=(__bf16)a.x; o0[1]=(__bf16)a.y; o0[2]=(__bf16)a.z; o0[3]=(__bf16)a.w;
        o0[4]=(__bf16)bb.x; o0[5]=(__bf16)bb.y; o0[6]=(__bf16)bb.z; o0[7]=(__bf16)bb.w;
        o1[0]=(__bf16)cc.x; o1[1]=(__bf16)cc.y; o1[2]=(__bf16)cc.z; o1[3]=(__bf16)cc.w;
        o1[4]=(__bf16)dd.x; o1[5]=(__bf16)dd.y; o1[6]=(__bf16)dd.z; o1[7]=(__bf16)dd.w;
        *(bf16x8*)(p1b + (size_t)gid * 16)     = o0;
        *(bf16x8*)(p1b + (size_t)gid * 16 + 8) = o1;
    }

    {   // identical staging to knn_vals
        const float* x2 = xyz2 + ((size_t)b * M_PT + c * CHM) * 3;
        float x = x2[tid * 3], y = x2[tid * 3 + 1], z = x2[tid * 3 + 2];
        pos[tid] = make_float4(-2.f * x, -2.f * y, -2.f * z,
                               fmaf(x, x, fmaf(y, y, z * z)));
    }
    __syncthreads();

    const int q = b * N_Q + qb * 256 + tid;
    const float* q1 = xyz1 + (size_t)q * 3;
    float x1 = q1[0], y1 = q1[1], z1 = q1[2];

    // merge 8 chunk-triples (chunk-ascending, same order as old knn_merge)
    float v0 = 3.4e38f, v1 = 3.4e38f, v2 = 3.4e38f;
#pragma unroll
    for (int cc = 0; cc < NCH; ++cc) {
        float4 t = vals4[(size_t)cc * R_TOT + q];
#pragma unroll
        for (int k = 0; k < 3; ++k) {
            float d  = (k == 0) ? t.x : (k == 1) ? t.y : t.z;
            float n0 = fminf(d, v0);
            float n1 = __builtin_amdgcn_fmed3f(d, v0, v1);
            float n2 = __builtin_amdgcn_fmed3f(d, v1, v2);
            v0 = n0; v1 = n1; v2 = n2;
        }
    }
    if (c == 0) {   // weights written once per query
        float n1q = fmaf(x1, x1, fmaf(y1, y1, z1 * z1));
        float r0 = 1.f / ((v0 + n1q) + 1e-8f);
        float r1 = 1.f / ((v1 + n1q) + 1e-8f);
        float r2 = 1.f / ((v2 + n1q) + 1e-8f);
        float rs = 1.f / (r0 + r1 + r2);
        w4[q] = make_float4(r0 * rs, r1 * rs, r2 * rs, 0.f);
    }

    // rescan chunk for indices (bitwise-identical d'; min keeps earliest j)
    int i0 = 0x7fffffff, i1 = 0x7fffffff, i2 = 0x7fffffff;
    const int jb = c * CHM;
#pragma unroll 4
    for (int j = 0; j < CHM; ++j) {
        float4 p = pos[j];
        float d  = fmaf(p.x, x1, fmaf(p.y, y1, fmaf(p.z, z1, p.w)));
        if (d <= v2) {               // rare: exec-mask + execz skip
            const int jj = jb + j;
            i0 = min(i0, (d == v0) ? jj : 0x7fffffff);
            i1 = min(i1, (d == v1) ? jj : 0x7fffffff);
            i2 = min(i2, (d == v2) ? jj : 0x7fffffff);
        }
    }
    ci4[(size_t)c * R_TOT + q] = make_int4(i0, i1, i2, 0);
}

// ---------------------------------------------------------------------------
// bf16 MFMA GEMM (m97 structure), optional fused BN-stats partials.
// C stride is H_OUT=256 for all uses (Z, y2).  grid = (rows/128)*2.
// ---------------------------------------------------------------------------
template <int K, bool STATS>
__global__ __launch_bounds__(256, 2) void gemm_bt(const __bf16* __restrict__ A,
                                                  const __bf16* __restrict__ Bw,
                                                  __bf16* __restrict__ Cout,
                                                  float* __restrict__ partS,
                                                  float* __restrict__ partQ) {
    __shared__ __attribute__((aligned(16))) __bf16 As[128 * 32];
    __shared__ __attribute__((aligned(16))) __bf16 Bs[128 * 32];
    const int tid  = threadIdx.x;
    const int wave = tid >> 6, lane = tid & 63;
    const int wm = wave >> 1, wn = wave & 1;
    const int quad = lane >> 4, r16 = lane & 15;
    const int bx = blockIdx.x & 1, by = blockIdx.x >> 1;
    const int l4 = lane >> 2, lk = (lane & 3) * 8;

    f32x4 acc[4][4] = {};

    const __bf16* gA = A  + (size_t)(by * 128 + wave * 32 + l4) * K + lk;
    const __bf16* gB = Bw + (size_t)(bx * 128 + wave * 32 + l4) * K + lk;
    char* lA = (char*)As + wave * 2048;
    char* lB = (char*)Bs + wave * 2048;

    for (int k0 = 0; k0 < K; k0 += 32) {
        async_copy16(gA + k0,                  lA);
        async_copy16(gA + k0 + (size_t)16 * K, lA + 1024);
        async_copy16(gB + k0,                  lB);
        async_copy16(gB + k0 + (size_t)16 * K, lB + 1024);
        __syncthreads();

        bf16x8 af[4], bf[4];
#pragma unroll
        for (int t = 0; t < 4; ++t)
            af[t] = *(const bf16x8*)(As + (wm * 64 + t * 16 + r16) * 32 + quad * 8);
#pragma unroll
        for (int u = 0; u < 4; ++u)
            bf[u] = *(const bf16x8*)(Bs + (wn * 64 + u * 16 + r16) * 32 + quad * 8);
#pragma unroll
        for (int t = 0; t < 4; ++t)
#pragma unroll
            for (int u = 0; u < 4; ++u)
                acc[t][u] = __builtin_amdgcn_mfma_f32_16x16x32_bf16(af[t], bf[u], acc[t][u], 0, 0, 0);
        __syncthreads();
    }

    // C/D layout col=lane&15, row=(lane>>4)*4+reg [m89-verified]
#pragma unroll
    for (int t = 0; t < 4; ++t) {
#pragma unroll
        for (int u = 0; u < 4; ++u) {
            const int col = bx * 128 + wn * 64 + u * 16 + r16;
#pragma unroll
            for (int r = 0; r < 4; ++r) {
                const int row = by * 128 + wm * 64 + t * 16 + quad * 4 + r;
                Cout[(size_t)row * H_OUT + col] = (__bf16)acc[t][u][r];
            }
        }
    }

    if constexpr (STATS) {
        float* redS = (float*)As;          // [col(128)][slot(8)]
        float* redQ = ((float*)As) + 1024;
        const int slot = wm * 4 + quad;
#pragma unroll
        for (int u = 0; u < 4; ++u) {
            float s = 0.f, qq = 0.f;
#pragma unroll
            for (int t = 0; t < 4; ++t)
#pragma unroll
                for (int r = 0; r < 4; ++r) { float v = acc[t][u][r]; s += v; qq = fmaf(v, v, qq); }
            const int col = wn * 64 + u * 16 + r16;
            redS[col * 8 + slot] = s;
            redQ[col * 8 + slot] = qq;
        }
        __syncthreads();
        if (tid < 128) {
            float s = 0.f, qq = 0.f;
#pragma unroll
            for (int k = 0; k < 8; ++k) { s += redS[tid * 8 + k]; qq += redQ[tid * 8 + k]; }
            partS[(size_t)blockIdx.x * 128 + tid] = s;
            partQ[(size_t)blockIdx.x * 128 + tid] = qq;
        }
    }
}

// ---------------------------------------------------------------------------
// GEMM-A (K=128) + fused interpolation epilogue + BN-stats:
//   y1 = p1b @ wb1a^T + sum_k w_k * Z[idx_k]      (linearity of interp)
// Z rows are L2-resident (8.4 MB); gathers are 16-lane-contiguous 2B loads.
// grid = 512*2 = 1024 blocks of 256.
// ---------------------------------------------------------------------------
__global__ __launch_bounds__(256, 2) void gemm_a_int(
    const __bf16* __restrict__ A,  const __bf16* __restrict__ Bw,
    const __bf16* __restrict__ zb, const int4* __restrict__ ci4,
    const float4* __restrict__ w4, __bf16* __restrict__ Cout,
    float* __restrict__ partS, float* __restrict__ partQ) {
    constexpr int K = C1;   // 128
    __shared__ __attribute__((aligned(16))) __bf16 As[128 * 32];
    __shared__ __attribute__((aligned(16))) __bf16 Bs[128 * 32];
    const int tid  = threadIdx.x;
    const int wave = tid >> 6, lane = tid & 63;
    const int wm = wave >> 1, wn = wave & 1;
    const int quad = lane >> 4, r16 = lane & 15;
    const int bx = blockIdx.x & 1, by = blockIdx.x >> 1;
    const int l4 = lane >> 2, lk = (lane & 3) * 8;

    f32x4 acc[4][4] = {};

    const __bf16* gA = A  + (size_t)(by * 128 + wave * 32 + l4) * K + lk;
    const __bf16* gB = Bw + (size_t)(bx * 128 + wave * 32 + l4) * K + lk;
    char* lA = (char*)As + wave * 2048;
    char* lB = (char*)Bs + wave * 2048;

    for (int k0 = 0; k0 < K; k0 += 32) {
        async_copy16(gA + k0,                  lA);
        async_copy16(gA + k0 + (size_t)16 * K, lA + 1024);
        async_copy16(gB + k0,                  lB);
        async_copy16(gB + k0 + (size_t)16 * K, lB + 1024);
        __syncthreads();

        bf16x8 af[4], bf[4];
#pragma unroll
        for (int t = 0; t < 4; ++t)
            af[t] = *(const bf16x8*)(As + (wm * 64 + t * 16 + r16) * 32 + quad * 8);
#pragma unroll
        for (int u = 0; u < 4; ++u)
            bf[u] = *(const bf16x8*)(Bs + (wn * 64 + u * 16 + r16) * 32 + quad * 8);
#pragma unroll
        for (int t = 0; t < 4; ++t)
#pragma unroll
            for (int u = 0; u < 4; ++u)
                acc[t][u] = __builtin_amdgcn_mfma_f32_16x16x32_bf16(af[t], bf[u], acc[t][u], 0, 0, 0);
        __syncthreads();
    }

    // stage per-row (idx0..2, w0..2) into As (4 KB of the free 8 KB)
    if (tid < 128) {
        const int q = by * 128 + tid;
        int i0 = 0x7fffffff, i1 = 0x7fffffff, i2 = 0x7fffffff;
#pragma unroll
        for (int cc = 0; cc < NCH; ++cc) {
            int4 t4 = ci4[(size_t)cc * R_TOT + q];
            i0 = min(i0, t4.x); i1 = min(i1, t4.y); i2 = min(i2, t4.z);
        }
        float4 w = w4[q];
        ((int4*)As)[tid * 2]       = make_int4(i0, i1, i2, 0);
        ((float4*)As)[tid * 2 + 1] = make_float4(w.x, w.y, w.z, 0.f);
    }
    __syncthreads();

    // add interpolated Z rows into the accumulators
    const int bbase = (by >> 6) * M_PT;   // 64 row-blocks per batch
#pragma unroll
    for (int t = 0; t < 4; ++t) {
#pragma unroll
        for (int r = 0; r < 4; ++r) {
            const int rl = wm * 64 + t * 16 + quad * 4 + r;   // row-in-block
            const int4   ii = ((const int4*)As)[rl * 2];      // broadcast read
            const float4 ww = ((const float4*)As)[rl * 2 + 1];
            const __bf16* z0 = zb + (size_t)(bbase + ii.x) * H_OUT;
            const __bf16* z1 = zb + (size_t)(bbase + ii.y) * H_OUT;
            const __bf16* z2 = zb + (size_t)(bbase + ii.z) * H_OUT;
#pragma unroll
            for (int u = 0; u < 4; ++u) {
                const int col = bx * 128 + wn * 64 + u * 16 + r16;
                acc[t][u][r] += ww.x * (float)z0[col] + ww.y * (float)z1[col]
                              + ww.z * (float)z2[col];
            }
        }
    }

    // C store (bf16 y1)
#pragma unroll
    for (int t = 0; t < 4; ++t) {
#pragma unroll
        for (int u = 0; u < 4; ++u) {
            const int col = bx * 128 + wn * 64 + u * 16 + r16;
#pragma unroll
            for (int r = 0; r < 4; ++r) {
                const int row = by * 128 + wm * 64 + t * 16 + quad * 4 + r;
                Cout[(size_t)row * H_OUT + col] = (__bf16)acc[t][u][r];
            }
        }
    }

    __syncthreads();   // idx/w reads done before stats overwrite As
    float* redS = (float*)As;
    float* redQ = ((float*)As) + 1024;
    const int slot = wm * 4 + quad;
#pragma unroll
    for (int u = 0; u < 4; ++u) {
        float s = 0.f, qq = 0.f;
#pragma unroll
        for (int t = 0; t < 4; ++t)
#pragma unroll
            for (int r = 0; r < 4; ++r) { float v = acc[t][u][r]; s += v; qq = fmaf(v, v, qq); }
        const int col = wn * 64 + u * 16 + r16;
        redS[col * 8 + slot] = s;
        redQ[col * 8 + slot] = qq;
    }
    __syncthreads();
    if (tid < 128) {
        float s = 0.f, qq = 0.f;
#pragma unroll
        for (int k = 0; k < 8; ++k) { s += redS[tid * 8 + k]; qq += redQ[tid * 8 + k]; }
        partS[(size_t)blockIdx.x * 128 + tid] = s;
        partQ[(size_t)blockIdx.x * 128 + tid] = qq;
    }
}

// ---------------------------------------------------------------------------
// fold per-block partials -> per-channel scale/shift.  One block per channel.
// channel c lives in gemm-blocks bid = p*2 + (c>>7), entry (c&127); p<512.
// ---------------------------------------------------------------------------
__global__ __launch_bounds__(256) void bn_finalize(const float* __restrict__ pS,
                                                   const float* __restrict__ pQ,
                                                   const float* __restrict__ gamma,
                                                   const float* __restrict__ beta,
                                                   float* __restrict__ sc,
                                                   float* __restrict__ sh) {
    __shared__ float rs[256], rq[256];
    const int c = blockIdx.x;
    const int t = threadIdx.x;
    const int half = c >> 7, lo = c & 127;
    const size_t o1 = (size_t)(2 * t + half) * 128 + lo;
    const size_t o2 = (size_t)(2 * (t + 256) + half) * 128 + lo;
    rs[t] = pS[o1] + pS[o2];
    rq[t] = pQ[o1] + pQ[o2];
    __syncthreads();
    for (int k = 128; k > 0; k >>= 1) {
        if (t < k) { rs[t] += rs[t + k]; rq[t] += rq[t + k]; }
        __syncthreads();
    }
    if (t == 0) {
        const float inv = 1.f / (float)R_TOT;
        float mean = rs[0] * inv;
        float var  = rq[0] * inv - mean * mean;
        float a    = gamma[c] * rsqrtf(var + 1e-5f);
        sc[c] = a;
        sh[c] = beta[c] - mean * a;
    }
}

// ---------------------------------------------------------------------------
// apply BN+ReLU in place (bf16, layer-1 intermediate)
// ---------------------------------------------------------------------------
__global__ __launch_bounds__(256) void apply_bf16(__bf16* __restrict__ y,
                                                  const float* __restrict__ sc,
                                                  const float* __restrict__ sh) {
    __shared__ float scs[256], shs[256];
    scs[threadIdx.x] = sc[threadIdx.x];
    shs[threadIdx.x] = sh[threadIdx.x];
    __syncthreads();
    size_t i = ((size_t)blockIdx.x * 256 + threadIdx.x) * 8;
    int c0 = (int)(i & 255);
    bf16x8 v = *(const bf16x8*)(y + i);
#pragma unroll
    for (int e = 0; e < 8; ++e) {
        float f = fmaf((float)v[e], scs[c0 + e], shs[c0 + e]);
        v[e] = (__bf16)fmaxf(f, 0.f);
    }
    *(bf16x8*)(y + i) = v;
}

// ---------------------------------------------------------------------------
// apply BN+ReLU reading bf16 y2, writing fp32 output
// ---------------------------------------------------------------------------
__global__ __launch_bounds__(256) void apply_out(const __bf16* __restrict__ y,
                                                 const float* __restrict__ sc,
                                                 const float* __restrict__ sh,
                                                 float* __restrict__ out) {
    __shared__ float scs[256], shs[256];
    scs[threadIdx.x] = sc[threadIdx.x];
    shs[threadIdx.x] = sh[threadIdx.x];
    __syncthreads();
    size_t i = ((size_t)blockIdx.x * 256 + threadIdx.x) * 8;
    int c0 = (int)(i & 255);
    bf16x8 v = *(const bf16x8*)(y + i);
    f32x4 o0, o1;
#pragma unroll
    for (int e = 0; e < 4; ++e)
        o0[e] = fmaxf(fmaf((float)v[e], scs[c0 + e], shs[c0 + e]), 0.f);
#pragma unroll
    for (int e = 0; e < 4; ++e)
        o1[e] = fmaxf(fmaf((float)v[4 + e], scs[c0 + 4 + e], shs[c0 + 4 + e]), 0.f);
    *(f32x4*)(out + i)     = o0;
    *(f32x4*)(out + i + 4) = o1;
}

// ---------------------------------------------------------------------------
extern "C" void kernel_launch(void* const* d_in, const int* in_sizes, int n_in,
                              void* d_out, int out_size, void* d_ws, size_t ws_size,
                              hipStream_t stream) {
    const float* xyz1 = (const float*)d_in[0];
    const float* xyz2 = (const float*)d_in[1];
    const float* p1   = (const float*)d_in[2];
    const float* p2   = (const float*)d_in[3];
    const float* W1   = (const float*)d_in[4];
    // d_in[5] = b1  (cancels in batch-norm)
    const float* g1   = (const float*)d_in[6];
    const float* be1  = (const float*)d_in[7];
    const float* W2   = (const float*)d_in[8];
    // d_in[9] = b2  (cancels in batch-norm)
    const float* g2   = (const float*)d_in[10];
    const float* be2  = (const float*)d_in[11];
    float* out = (float*)d_out;

    // workspace layout (16B aligned), max 76.9 MB (< proven 84.7):
    //   zb overlays vals4 (dead after knn_recover; zb born at gemmZ)
    //   y2b overlays ci4/zb/w4/p2b + p1b-head (all dead after gemm_a_int)
    char* ws = (char*)d_ws;
    __bf16* y1b   = (__bf16*)(ws);                     // 33,554,432
    int4*   ci4   = (int4*)  (ws + 33554432);          //  8,388,608
    float4* vals4 = (float4*)(ws + 41943040);          //  8,388,608
    __bf16* zb    = (__bf16*)(ws + 41943040);          //  8,388,608 (overlay)
    float4* w4    = (float4*)(ws + 50331648);          //  1,048,576
    __bf16* p2b   = (__bf16*)(ws + 51380224);          //  8,388,608
    __bf16* p1b   = (__bf16*)(ws + 59768832);          // 16,777,216
    __bf16* y2b   = (__bf16*)(ws + 33554432);          // 33,554,432 (overlay)
    __bf16* wb1a  = (__bf16*)(ws + 76546048);          //     65,536
    __bf16* wb1b  = (__bf16*)(ws + 76611584);          //    131,072
    __bf16* wb2   = (__bf16*)(ws + 76742656);          //    131,072
    float*  sc1   = (float*) (ws + 76873728);
    float*  sh1   = sc1 + 256;
    float*  sc2   = sc1 + 512;
    float*  sh2   = sc1 + 768;

    float* partS1 = (float*)d_out;            // d_out dead until apply_out
    float* partQ1 = partS1 + 131072;
    float* partS2 = partS1 + 262144;
    float* partQ2 = partS1 + 393216;

    knn_vals<<<2048, 256, 0, stream>>>(xyz1, xyz2, p2, W1, W2,
                                       p2b, wb1a, wb1b, wb2, vals4);
    knn_recover<<<2048, 256, 0, stream>>>(xyz1, xyz2, p1, vals4, p1b, w4, ci4);

    gemm_bt<C2, false><<<256, 256, 0, stream>>>(p2b, wb1b, zb, nullptr, nullptr);
    gemm_a_int<<<1024, 256, 0, stream>>>(p1b, wb1a, zb, ci4, w4, y1b,
                                         partS1, partQ1);
    bn_finalize<<<256, 256, 0, stream>>>(partS1, partQ1, g1, be1, sc1, sh1);
    apply_bf16<<<8192, 256, 0, stream>>>(y1b, sc1, sh1);

    gemm_bt<H_OUT, true><<<1024, 256, 0, stream>>>(y1b, wb2, y2b, partS2, partQ2);
    bn_finalize<<<256, 256, 0, stream>>>(partS2, partQ2, g2, be2, sc2, sh2);
    apply_out<<<8192, 256, 0, stream>>>(y2b, sc2, sh2, out);
}